// Round 4
// baseline (777.513 us; speedup 1.0000x reference)
//
#include <hip/hip_runtime.h>
#include <hip/hip_bf16.h>

typedef short bf16x8 __attribute__((ext_vector_type(8)));
typedef float f32x4 __attribute__((ext_vector_type(4)));
typedef int int4v __attribute__((ext_vector_type(4)));

#define OMEGA 30.0f

// ---------------- prep: transpose xi [B,C,H,W] f32 -> xt [B,HW,C] bf16 ----------------
__global__ __launch_bounds__(256) void k_transpose(const float* __restrict__ xi,
                                                   __hip_bfloat16* __restrict__ xt) {
  __shared__ float tile[32][33];
  int hw0 = blockIdx.x * 32, c0 = blockIdx.y * 32, b = blockIdx.z;
  int t = threadIdx.x;
  int r = t >> 5, cc = t & 31;
  const float* src = xi + (((size_t)b * 128 + c0) << 14) + hw0;
#pragma unroll
  for (int i = 0; i < 4; ++i)
    tile[r + i * 8][cc] = src[(size_t)(r + i * 8) * 16384 + cc];
  __syncthreads();
  __hip_bfloat16* dst = xt + (((size_t)b * 16384 + hw0) << 7) + c0;
#pragma unroll
  for (int i = 0; i < 4; ++i)
    dst[(size_t)(r + i * 8) * 128 + cc] = __float2bfloat16(tile[cc][r + i * 8]);
}

// ---------------- prep: W0 rows 0..3199 -> wt2[f][n][c] = W0[c*25+f][n] ----------------
__global__ __launch_bounds__(256) void k_prepw0(const float* __restrict__ W0,
                                                __hip_bfloat16* __restrict__ wt2) {
  __shared__ float tile[128][33];
  int f = blockIdx.x, nb = blockIdx.y;
  int t = threadIdx.x;
  int nn = t & 31, cr = t >> 5;  // cr 0..7
#pragma unroll
  for (int i = 0; i < 16; ++i) {
    int c = cr * 16 + i;
    tile[c][nn] = W0[(size_t)(c * 25 + f) * 256 + nb * 32 + nn];
  }
  __syncthreads();
#pragma unroll
  for (int i = 0; i < 16; ++i) {
    int idx = i * 256 + t;
    int n = idx >> 7, c = idx & 127;
    wt2[(size_t)f * 32768 + (size_t)(nb * 32 + n) * 128 + c] = __float2bfloat16(tile[c][n]);
  }
}

// ---------------- prep: w1t[n][k] = W1[k][n], w2t likewise; grid (8,8,2) ----------------
__global__ __launch_bounds__(256) void k_prepw12(const float* __restrict__ W1,
                                                 const float* __restrict__ W2,
                                                 __hip_bfloat16* __restrict__ w1t,
                                                 __hip_bfloat16* __restrict__ w2t) {
  __shared__ float tile[32][33];
  const float* src = blockIdx.z ? W2 : W1;
  __hip_bfloat16* dst = blockIdx.z ? w2t : w1t;
  int k0 = blockIdx.x * 32, n0 = blockIdx.y * 32;
  int t = threadIdx.x;
  int r = t >> 5, cc = t & 31;
#pragma unroll
  for (int i = 0; i < 4; ++i)
    tile[r + i * 8][cc] = src[(size_t)(k0 + r + i * 8) * 256 + n0 + cc];
  __syncthreads();
#pragma unroll
  for (int i = 0; i < 4; ++i)
    dst[(size_t)(n0 + r + i * 8) * 256 + k0 + cc] = __float2bfloat16(tile[cc][r + i * 8]);
}

// ---------------- conv 5x5 (128->256) + coords + bias + sin ----------------
// grid (128, 4), block 256 (4 waves). Static LDS 59392 B -> 2 blocks/CU.
// K=3200 split as 50 tap-halves (25 taps x 2 channel-halves of 64).
__global__ __launch_bounds__(256) void k_conv(const __hip_bfloat16* __restrict__ xt,
                                              const __hip_bfloat16* __restrict__ wt2,
                                              const float* __restrict__ W0,
                                              const float* __restrict__ b0,
                                              __hip_bfloat16* __restrict__ h0) {
  __shared__ __align__(16) char Al[400 * 128];  // [pos 20x20][64ch], swz: slot^(pos&7)
  __shared__ __align__(16) char Bl[64 * 128];   // [n][64ch],        swz: slot^(n&7)
  int tid = threadIdx.x;
  int bx = blockIdx.x;
  int b = bx >> 6, tr = (bx >> 3) & 7, tc = bx & 7;
  int n0 = blockIdx.y << 6;
  int lane = tid & 63, wave = tid >> 6;
  int lr = lane & 15, lg = lane >> 4;

  f32x4 acc[4][4] = {};

  // prefetch B(t=0): f=0, cb=0
  int4v breg[2];
#pragma unroll
  for (int j = 0; j < 2; ++j) {
    int idx = j * 256 + tid;
    int n = idx >> 3, s = idx & 7;
    breg[j] = *(const int4v*)(wt2 + (size_t)(n0 + n) * 128 + s * 8);
  }

  for (int t = 0; t < 50; ++t) {
    int cb = (t >= 25) ? 1 : 0;
    int f = t - cb * 25;
    if (f == 0) {
      __syncthreads();  // previous halo readers done
      for (int idx = tid; idx < 3200; idx += 256) {
        int pos = idx >> 3, s = idx & 7;
        int py = pos / 20, px = pos - py * 20;
        int gh = (tr << 4) + py - 2, gw = (tc << 4) + px - 2;
        int4v v = {0, 0, 0, 0};
        if ((unsigned)gh < 128u && (unsigned)gw < 128u)
          v = *(const int4v*)(xt + (((size_t)((b << 14) + (gh << 7) + gw)) << 7) + cb * 64 + s * 8);
        *(int4v*)(Al + pos * 128 + ((s ^ (pos & 7)) << 4)) = v;
      }
    }
    __syncthreads();  // readers of B(t-1) done
#pragma unroll
    for (int j = 0; j < 2; ++j) {
      int idx = j * 256 + tid;
      int n = idx >> 3, s = idx & 7;
      *(int4v*)(Bl + n * 128 + ((s ^ (n & 7)) << 4)) = breg[j];
    }
    if (t < 49) {  // prefetch B(t+1) -> regs; latency hides under MFMA below
      int t2 = t + 1;
      int cb2 = (t2 >= 25) ? 1 : 0;
      int f2 = t2 - cb2 * 25;
#pragma unroll
      for (int j = 0; j < 2; ++j) {
        int idx = j * 256 + tid;
        int n = idx >> 3, s = idx & 7;
        breg[j] = *(const int4v*)(wt2 + (size_t)(f2 * 256 + n0 + n) * 128 + cb2 * 64 + s * 8);
      }
    }
    __syncthreads();  // halo + B(t) visible
    int fy = f / 5, fx = f - fy * 5;
    int px = lr + fx;
#pragma unroll
    for (int ks = 0; ks < 2; ++ks) {
      int sk = (ks << 2) + lg;  // 0..7
      bf16x8 a[4], bw[4];
#pragma unroll
      for (int mi = 0; mi < 4; ++mi) {
        int pos = ((wave << 2) + mi + fy) * 20 + px;
        a[mi] = *(const bf16x8*)(Al + pos * 128 + ((sk ^ (pos & 7)) << 4));
      }
#pragma unroll
      for (int ni = 0; ni < 4; ++ni) {
        int nr = (ni << 4) + lr;
        bw[ni] = *(const bf16x8*)(Bl + nr * 128 + ((sk ^ (nr & 7)) << 4));
      }
#pragma unroll
      for (int mi = 0; mi < 4; ++mi)
#pragma unroll
        for (int ni = 0; ni < 4; ++ni)
          acc[mi][ni] = __builtin_amdgcn_mfma_f32_16x16x32_bf16(a[mi], bw[ni], acc[mi][ni], 0, 0, 0);
    }
  }

  // ---- epilogue: z = acc + b0 + gx*wA + gy*wB; sin(30 z); LDS bounce -> coalesced 16B stores
  float wA[4], wB[4], bb[4];
#pragma unroll
  for (int ni = 0; ni < 4; ++ni) {
    int n = n0 + (ni << 4) + lr;
    wA[ni] = W0[3200 * 256 + n];
    wB[ni] = W0[3201 * 256 + n];
    bb[ni] = b0[n];
  }
  __syncthreads();  // all waves done reading Al before we overwrite it as staging
  char* stg = Al + wave * 9216;  // per-wave [64 r][144B]; r = mi*16 + pc, cols n 0..63
#pragma unroll
  for (int mi = 0; mi < 4; ++mi) {
    int h = (tr << 4) + (wave << 2) + mi;
    float gy = -1.f + (2.f / 127.f) * (float)h;
#pragma unroll
    for (int j = 0; j < 4; ++j) {
      int pc = (lg << 2) + j;
      int w = (tc << 4) + pc;
      float gx = -1.f + (2.f / 127.f) * (float)w;
      int r = (mi << 4) + pc;
#pragma unroll
      for (int ni = 0; ni < 4; ++ni) {
        float v = acc[mi][ni][j] + bb[ni] + gx * wA[ni] + gy * wB[ni];
        unsigned short bits = __hip_bfloat16_raw(__float2bfloat16(sinf(OMEGA * v))).x;
        int n = (ni << 4) + lr;
        int c = n >> 3;
        *(unsigned short*)(stg + r * 144 + (((c ^ (r & 7)) << 4) | ((n & 7) << 1))) = bits;
      }
    }
  }
  // wave-local read-back: 8 x 1KB fully-coalesced stores (each 64B line written whole)
#pragma unroll
  for (int i = 0; i < 8; ++i) {
    int r = (i << 3) + (lane >> 3);
    int c = lane & 7;
    int4v v = *(const int4v*)(stg + r * 144 + ((c ^ (r & 7)) << 4));
    int m = (b << 14) + (((tr << 4) + (wave << 2) + (r >> 4)) << 7) + (tc << 4) + (r & 15);
    *(int4v*)(h0 + (size_t)m * 256 + n0 + c * 8) = v;
  }
}

// ---------------- hidden layer: h_out = sin(30*(h_in @ W + b)) ----------------
// grid (256, 2), block 256 (4 waves 2x2). Static LDS 65536 B.
__global__ __launch_bounds__(256) void k_layer(const __hip_bfloat16* __restrict__ hin,
                                               const __hip_bfloat16* __restrict__ wt,
                                               const float* __restrict__ bias,
                                               __hip_bfloat16* __restrict__ hout) {
  __shared__ __align__(16) char S[65536];
  char* Al = S;            // [128 m][128ch half, 256B], swz: s^(r&15)
  char* Bl = S + 32768;    // [128 n][128ch half, 256B]
  int tid = threadIdx.x;
  int m0 = blockIdx.x << 7, n0 = blockIdx.y << 7;
  int lane = tid & 63, wave = tid >> 6;
  int lr = lane & 15, lg = lane >> 4;
  int wm = (wave >> 1) << 6, wn = (wave & 1) << 6;
  f32x4 acc[4][4] = {};

  for (int cb = 0; cb < 2; ++cb) {
    if (cb) __syncthreads();  // phase-0 readers done
#pragma unroll
    for (int i = 0; i < 8; ++i) {
      int idx = i * 256 + tid;  // 0..2047
      int r = idx >> 4, s = idx & 15;
      *(int4v*)(Al + r * 256 + ((s ^ (r & 15)) << 4)) =
          *(const int4v*)(hin + (size_t)(m0 + r) * 256 + cb * 128 + s * 8);
      *(int4v*)(Bl + r * 256 + ((s ^ (r & 15)) << 4)) =
          *(const int4v*)(wt + (size_t)(n0 + r) * 256 + cb * 128 + s * 8);
    }
    __syncthreads();
#pragma unroll
    for (int ks = 0; ks < 4; ++ks) {
      int sk = (ks << 2) + lg;  // 0..15
      bf16x8 a[4], bw[4];
#pragma unroll
      for (int mi = 0; mi < 4; ++mi) {
        int r = wm + (mi << 4) + lr;
        a[mi] = *(const bf16x8*)(Al + r * 256 + ((sk ^ (r & 15)) << 4));
      }
#pragma unroll
      for (int ni = 0; ni < 4; ++ni) {
        int r = wn + (ni << 4) + lr;
        bw[ni] = *(const bf16x8*)(Bl + r * 256 + ((sk ^ (r & 15)) << 4));
      }
#pragma unroll
      for (int mi = 0; mi < 4; ++mi)
#pragma unroll
        for (int ni = 0; ni < 4; ++ni)
          acc[mi][ni] = __builtin_amdgcn_mfma_f32_16x16x32_bf16(a[mi], bw[ni], acc[mi][ni], 0, 0, 0);
    }
  }

  float bb[4];
#pragma unroll
  for (int ni = 0; ni < 4; ++ni) bb[ni] = bias[n0 + wn + (ni << 4) + lr];

  // ---- epilogue: LDS bounce -> coalesced 16B stores (wave-local slice [64 r][144B])
  __syncthreads();  // all waves done reading Al/Bl
  char* stg = S + wave * 9216;
#pragma unroll
  for (int mi = 0; mi < 4; ++mi)
#pragma unroll
    for (int j = 0; j < 4; ++j) {
      int r = (mi << 4) + (lg << 2) + j;  // m within wave's 64
#pragma unroll
      for (int ni = 0; ni < 4; ++ni) {
        unsigned short bits =
            __hip_bfloat16_raw(__float2bfloat16(sinf(OMEGA * (acc[mi][ni][j] + bb[ni])))).x;
        int n = (ni << 4) + lr;
        int c = n >> 3;
        *(unsigned short*)(stg + r * 144 + (((c ^ (r & 7)) << 4) | ((n & 7) << 1))) = bits;
      }
    }
#pragma unroll
  for (int i = 0; i < 8; ++i) {
    int r = (i << 3) + (lane >> 3);
    int c = lane & 7;
    int4v v = *(const int4v*)(stg + r * 144 + ((c ^ (r & 7)) << 4));
    size_t m = (size_t)(m0 + wm + r);
    *(int4v*)(hout + (m << 8) + n0 + wn + c * 8) = v;
  }
}

// ---------------- head: out[b][o][h][w] = h2 @ W3 + b3 ----------------
__global__ __launch_bounds__(256) void k_head(const __hip_bfloat16* __restrict__ h2,
                                              const float* __restrict__ W3,
                                              const float* __restrict__ b3,
                                              float* __restrict__ out) {
  __shared__ __align__(16) __hip_bfloat16 hl[64 * 256];
  __shared__ float w3l[768];
  int tid = threadIdx.x;
  int m0 = blockIdx.x << 6;
#pragma unroll
  for (int i = 0; i < 8; ++i) {
    int idx = i * 256 + tid;
    *(int4v*)((char*)hl + idx * 16) = *(const int4v*)(h2 + ((size_t)m0 << 8) + idx * 8);
  }
  for (int i = tid; i < 768; i += 256) w3l[i] = W3[i];
  __syncthreads();
  int pix = tid >> 2, o = tid & 3;
  if (o < 3) {
    float acc = b3[o];
    for (int c0 = 0; c0 < 32; ++c0) {
      int c = (c0 + pix) & 31;
      bf16x8 v = *(const bf16x8*)((char*)hl + pix * 512 + c * 16);
#pragma unroll
      for (int j = 0; j < 8; ++j) {
        unsigned short u = (unsigned short)v[j];
        float hv = __uint_as_float((unsigned)u << 16);
        acc += hv * w3l[(c * 8 + j) * 3 + o];
      }
    }
    int m = m0 + pix;
    int b = m >> 14, hw = m & 16383;
    out[((b * 3 + o) << 14) + hw] = acc;
  }
}

extern "C" void kernel_launch(void* const* d_in, const int* in_sizes, int n_in,
                              void* d_out, int out_size, void* d_ws, size_t ws_size,
                              hipStream_t stream) {
  const float* xi = (const float*)d_in[0];
  const float* W0 = (const float*)d_in[1];
  const float* b0 = (const float*)d_in[2];
  const float* W1 = (const float*)d_in[3];
  const float* b1 = (const float*)d_in[4];
  const float* W2 = (const float*)d_in[5];
  const float* b2 = (const float*)d_in[6];
  const float* W3 = (const float*)d_in[7];
  const float* b3 = (const float*)d_in[8];
  float* out = (float*)d_out;
  char* ws = (char*)d_ws;

  __hip_bfloat16* xt  = (__hip_bfloat16*)(ws + 0);          //  8,388,608 B
  __hip_bfloat16* wt2 = (__hip_bfloat16*)(ws + 8388608);    //  1,638,400 B
  __hip_bfloat16* w1t = (__hip_bfloat16*)(ws + 10027008);   //    131,072 B
  __hip_bfloat16* w2t = (__hip_bfloat16*)(ws + 10158080);   //    131,072 B
  __hip_bfloat16* h0  = (__hip_bfloat16*)(ws + 10289152);   // 16,777,216 B (reused as h2)
  __hip_bfloat16* h1  = (__hip_bfloat16*)(ws + 27066368);   // 16,777,216 B

  k_transpose<<<dim3(512, 4, 2), 256, 0, stream>>>(xi, xt);
  k_prepw0<<<dim3(25, 8), 256, 0, stream>>>(W0, wt2);
  k_prepw12<<<dim3(8, 8, 2), 256, 0, stream>>>(W1, W2, w1t, w2t);
  k_conv<<<dim3(128, 4), 256, 0, stream>>>(xt, wt2, W0, b0, h0);
  k_layer<<<dim3(256, 2), 256, 0, stream>>>(h0, w1t, b1, h1);
  k_layer<<<dim3(256, 2), 256, 0, stream>>>(h1, w2t, b2, h0);
  k_head<<<512, 256, 0, stream>>>(h0, W3, b3, out);
}

// Round 5
// 291.596 us; speedup vs baseline: 2.6664x; 2.6664x over previous
//
#include <hip/hip_runtime.h>
#include <hip/hip_bf16.h>

typedef short bf16x8 __attribute__((ext_vector_type(8)));
typedef float f32x4 __attribute__((ext_vector_type(4)));
typedef int int4v __attribute__((ext_vector_type(4)));

#define OMEGA 30.0f

// ---------------- prep: transpose xi [B,C,H,W] f32 -> xt [B,HW,C] bf16 ----------------
__global__ __launch_bounds__(256) void k_transpose(const float* __restrict__ xi,
                                                   __hip_bfloat16* __restrict__ xt) {
  __shared__ float tile[32][33];
  int hw0 = blockIdx.x * 32, c0 = blockIdx.y * 32, b = blockIdx.z;
  int t = threadIdx.x;
  int r = t >> 5, cc = t & 31;
  const float* src = xi + (((size_t)b * 128 + c0) << 14) + hw0;
#pragma unroll
  for (int i = 0; i < 4; ++i)
    tile[r + i * 8][cc] = src[(size_t)(r + i * 8) * 16384 + cc];
  __syncthreads();
  __hip_bfloat16* dst = xt + (((size_t)b * 16384 + hw0) << 7) + c0;
#pragma unroll
  for (int i = 0; i < 4; ++i)
    dst[(size_t)(r + i * 8) * 128 + cc] = __float2bfloat16(tile[cc][r + i * 8]);
}

// ---------------- prep: W0 rows 0..3199 -> wt2[f][n][c] = W0[c*25+f][n] ----------------
__global__ __launch_bounds__(256) void k_prepw0(const float* __restrict__ W0,
                                                __hip_bfloat16* __restrict__ wt2) {
  __shared__ float tile[128][33];
  int f = blockIdx.x, nb = blockIdx.y;
  int t = threadIdx.x;
  int nn = t & 31, cr = t >> 5;  // cr 0..7
#pragma unroll
  for (int i = 0; i < 16; ++i) {
    int c = cr * 16 + i;
    tile[c][nn] = W0[(size_t)(c * 25 + f) * 256 + nb * 32 + nn];
  }
  __syncthreads();
#pragma unroll
  for (int i = 0; i < 16; ++i) {
    int idx = i * 256 + t;
    int n = idx >> 7, c = idx & 127;
    wt2[(size_t)f * 32768 + (size_t)(nb * 32 + n) * 128 + c] = __float2bfloat16(tile[c][n]);
  }
}

// ---------------- prep: w1t[n][k] = W1[k][n], w2t likewise; grid (8,8,2) ----------------
__global__ __launch_bounds__(256) void k_prepw12(const float* __restrict__ W1,
                                                 const float* __restrict__ W2,
                                                 __hip_bfloat16* __restrict__ w1t,
                                                 __hip_bfloat16* __restrict__ w2t) {
  __shared__ float tile[32][33];
  const float* src = blockIdx.z ? W2 : W1;
  __hip_bfloat16* dst = blockIdx.z ? w2t : w1t;
  int k0 = blockIdx.x * 32, n0 = blockIdx.y * 32;
  int t = threadIdx.x;
  int r = t >> 5, cc = t & 31;
#pragma unroll
  for (int i = 0; i < 4; ++i)
    tile[r + i * 8][cc] = src[(size_t)(k0 + r + i * 8) * 256 + n0 + cc];
  __syncthreads();
#pragma unroll
  for (int i = 0; i < 4; ++i)
    dst[(size_t)(n0 + r + i * 8) * 256 + k0 + cc] = __float2bfloat16(tile[cc][r + i * 8]);
}

// ---------------- conv 5x5 (128->256) + coords + bias + sin ----------------
// grid (128, 4), block 256 (4 waves). Static LDS 47104 B -> 3 blocks/CU.
// Linear K-counter i in [0,100): rh=i/50 (output row-half), A-half=(i/25)&1,
// tap f=i%25. B(i): cb=(i/25)&1, f=i%25. B double-buffered, distance-2 prefetch,
// ONE barrier per iteration.
__global__ __launch_bounds__(256) void k_conv(const __hip_bfloat16* __restrict__ xt,
                                              const __hip_bfloat16* __restrict__ wt2,
                                              const float* __restrict__ W0,
                                              const float* __restrict__ b0,
                                              __hip_bfloat16* __restrict__ h0) {
  __shared__ __align__(16) char Al[240 * 128];   // [12 rows x 20 px][64ch], swz s^(pos&7)
  __shared__ __align__(16) char Bl[2][64 * 128]; // dbuf [n][64ch], swz s^(n&7)
  int tid = threadIdx.x;
  int bx = blockIdx.x;
  int b = bx >> 6, tr = (bx >> 3) & 7, tc = bx & 7;
  int n0 = blockIdx.y << 6;
  int lane = tid & 63, wave = tid >> 6;
  int lr = lane & 15, lg = lane >> 4;

  // epilogue constants (n-indexed, loop-invariant)
  float wA[4], wB[4], bb[4];
#pragma unroll
  for (int ni = 0; ni < 4; ++ni) {
    int n = n0 + (ni << 4) + lr;
    wA[ni] = W0[3200 * 256 + n];
    wB[ni] = W0[3201 * 256 + n];
    bb[ni] = b0[n];
  }

  int4v breg[2];
  auto loadB = [&](int i) {
    int cb = (i / 25) & 1, f = i % 25;
#pragma unroll
    for (int j = 0; j < 2; ++j) {
      int idx = j * 256 + tid;
      int n = idx >> 3, s = idx & 7;
      breg[j] = *(const int4v*)(wt2 + (size_t)(f * 256 + n0 + n) * 128 + cb * 64 + s * 8);
    }
  };
  auto writeB = [&](int i) {
    char* dst = Bl[i & 1];
#pragma unroll
    for (int j = 0; j < 2; ++j) {
      int idx = j * 256 + tid;
      int n = idx >> 3, s = idx & 7;
      *(int4v*)(dst + n * 128 + ((s ^ (n & 7)) << 4)) = breg[j];
    }
  };

  // prologue: B(0) into buf0, hold B(1) in regs
  loadB(0);
  writeB(0);
  loadB(1);

  f32x4 acc[2][4] = {};

  for (int rh = 0; rh < 2; ++rh) {
    for (int half = 0; half < 2; ++half) {
      // ---- stage A(rh, half): input rows rh*8-2 .. rh*8+9 (12 rows x 20 px x 64ch)
      __syncthreads();  // prior readers of Al (incl. epilogue bounce) done
#pragma unroll
      for (int ii = 0; ii < 8; ++ii) {
        int idx = ii * 256 + tid;
        if (idx < 1920) {
          int pos = idx >> 3, s = idx & 7;
          int py = pos / 20, px_ = pos - py * 20;
          int gh = (tr << 4) + (rh << 3) + py - 2, gw = (tc << 4) + px_ - 2;
          int4v v = {0, 0, 0, 0};
          if ((unsigned)gh < 128u && (unsigned)gw < 128u)
            v = *(const int4v*)(xt + (((size_t)((b << 14) + (gh << 7) + gw)) << 7) + half * 64 + s * 8);
          *(int4v*)(Al + pos * 128 + ((s ^ (pos & 7)) << 4)) = v;
        }
      }
      __syncthreads();

      for (int f = 0; f < 25; ++f) {
        int i = rh * 50 + half * 25 + f;
        if (i < 99) writeB(i + 1);   // B(i+1) -> buf((i+1)&1) from regs
        if (i < 98) loadB(i + 2);    // issue next prefetch (drained next iter)
        int fy = f / 5, fx = f - fy * 5;
        int px = lr + fx;
        char* Bbuf = Bl[i & 1];
#pragma unroll
        for (int ks = 0; ks < 2; ++ks) {
          int sk = (ks << 2) + lg;  // 0..7
          bf16x8 a[2], bw[4];
#pragma unroll
          for (int mi = 0; mi < 2; ++mi) {
            int fl = wave + (mi << 2);           // local output row 0..7
            int pos = (fl + fy) * 20 + px;
            a[mi] = *(const bf16x8*)(Al + pos * 128 + ((sk ^ (pos & 7)) << 4));
          }
#pragma unroll
          for (int ni = 0; ni < 4; ++ni) {
            int nr = (ni << 4) + lr;
            bw[ni] = *(const bf16x8*)(Bbuf + nr * 128 + ((sk ^ (nr & 7)) << 4));
          }
#pragma unroll
          for (int mi = 0; mi < 2; ++mi)
#pragma unroll
            for (int ni = 0; ni < 4; ++ni)
              acc[mi][ni] = __builtin_amdgcn_mfma_f32_16x16x32_bf16(a[mi], bw[ni], acc[mi][ni], 0, 0, 0);
        }
        __syncthreads();  // buf(i&1) readers done before iter i+1 overwrites it
      }
    }

    // ---- epilogue for this row-half: bias+coords+sin, LDS bounce, coalesced stores
    char* stg = Al + wave * 4096;  // per-wave 2 frags x [16 px][128B]
#pragma unroll
    for (int mi = 0; mi < 2; ++mi) {
      int fl = wave + (mi << 2);
      int H = (tr << 4) + (rh << 3) + fl;
      float gy = -1.f + (2.f / 127.f) * (float)H;
#pragma unroll
      for (int j = 0; j < 4; ++j) {
        int cpx = (lg << 2) + j;  // pixel column in tile
        int W = (tc << 4) + cpx;
        float gx = -1.f + (2.f / 127.f) * (float)W;
#pragma unroll
        for (int ni = 0; ni < 4; ++ni) {
          float v = acc[mi][ni][j] + bb[ni] + gx * wA[ni] + gy * wB[ni];
          unsigned short bits = __hip_bfloat16_raw(__float2bfloat16(sinf(OMEGA * v))).x;
          int n = (ni << 4) + lr;
          int c = n >> 3;
          *(unsigned short*)(stg + mi * 2048 + cpx * 128 + (((c ^ (cpx & 7)) << 4) | ((n & 7) << 1))) = bits;
        }
      }
    }
#pragma unroll
    for (int mi = 0; mi < 2; ++mi) {
      int fl = wave + (mi << 2);
      int H = (tr << 4) + (rh << 3) + fl;
#pragma unroll
      for (int i2 = 0; i2 < 2; ++i2) {
        int r = (i2 << 3) + (lane >> 3);  // pixel column
        int c = lane & 7;
        int4v v = *(const int4v*)(stg + mi * 2048 + r * 128 + ((c ^ (r & 7)) << 4));
        int m = (b << 14) + (H << 7) + (tc << 4) + r;
        *(int4v*)(h0 + (size_t)m * 256 + n0 + c * 8) = v;
      }
    }
    if (rh == 0) {
#pragma unroll
      for (int mi = 0; mi < 2; ++mi)
#pragma unroll
        for (int ni = 0; ni < 4; ++ni)
          acc[mi][ni] = f32x4{0.f, 0.f, 0.f, 0.f};
    }
  }
}

// ---------------- hidden layer: h_out = sin(30*(h_in @ W + b)) ----------------
// grid (256, 2), block 256 (4 waves 2x2). Static LDS 65536 B.
__global__ __launch_bounds__(256) void k_layer(const __hip_bfloat16* __restrict__ hin,
                                               const __hip_bfloat16* __restrict__ wt,
                                               const float* __restrict__ bias,
                                               __hip_bfloat16* __restrict__ hout) {
  __shared__ __align__(16) char S[65536];
  char* Al = S;            // [128 m][128ch half, 256B], swz: s^(r&15)
  char* Bl = S + 32768;    // [128 n][128ch half, 256B]
  int tid = threadIdx.x;
  int m0 = blockIdx.x << 7, n0 = blockIdx.y << 7;
  int lane = tid & 63, wave = tid >> 6;
  int lr = lane & 15, lg = lane >> 4;
  int wm = (wave >> 1) << 6, wn = (wave & 1) << 6;
  f32x4 acc[4][4] = {};

  for (int cb = 0; cb < 2; ++cb) {
    if (cb) __syncthreads();  // phase-0 readers done
#pragma unroll
    for (int i = 0; i < 8; ++i) {
      int idx = i * 256 + tid;  // 0..2047
      int r = idx >> 4, s = idx & 15;
      *(int4v*)(Al + r * 256 + ((s ^ (r & 15)) << 4)) =
          *(const int4v*)(hin + (size_t)(m0 + r) * 256 + cb * 128 + s * 8);
      *(int4v*)(Bl + r * 256 + ((s ^ (r & 15)) << 4)) =
          *(const int4v*)(wt + (size_t)(n0 + r) * 256 + cb * 128 + s * 8);
    }
    __syncthreads();
#pragma unroll
    for (int ks = 0; ks < 4; ++ks) {
      int sk = (ks << 2) + lg;  // 0..15
      bf16x8 a[4], bw[4];
#pragma unroll
      for (int mi = 0; mi < 4; ++mi) {
        int r = wm + (mi << 4) + lr;
        a[mi] = *(const bf16x8*)(Al + r * 256 + ((sk ^ (r & 15)) << 4));
      }
#pragma unroll
      for (int ni = 0; ni < 4; ++ni) {
        int r = wn + (ni << 4) + lr;
        bw[ni] = *(const bf16x8*)(Bl + r * 256 + ((sk ^ (r & 15)) << 4));
      }
#pragma unroll
      for (int mi = 0; mi < 4; ++mi)
#pragma unroll
        for (int ni = 0; ni < 4; ++ni)
          acc[mi][ni] = __builtin_amdgcn_mfma_f32_16x16x32_bf16(a[mi], bw[ni], acc[mi][ni], 0, 0, 0);
    }
  }

  float bb[4];
#pragma unroll
  for (int ni = 0; ni < 4; ++ni) bb[ni] = bias[n0 + wn + (ni << 4) + lr];

  // ---- epilogue: LDS bounce -> coalesced 16B stores (wave-local slice [64 r][144B])
  __syncthreads();  // all waves done reading Al/Bl
  char* stg = S + wave * 9216;
#pragma unroll
  for (int mi = 0; mi < 4; ++mi)
#pragma unroll
    for (int j = 0; j < 4; ++j) {
      int r = (mi << 4) + (lg << 2) + j;  // m within wave's 64
#pragma unroll
      for (int ni = 0; ni < 4; ++ni) {
        unsigned short bits =
            __hip_bfloat16_raw(__float2bfloat16(sinf(OMEGA * (acc[mi][ni][j] + bb[ni])))).x;
        int n = (ni << 4) + lr;
        int c = n >> 3;
        *(unsigned short*)(stg + r * 144 + (((c ^ (r & 7)) << 4) | ((n & 7) << 1))) = bits;
      }
    }
#pragma unroll
  for (int i = 0; i < 8; ++i) {
    int r = (i << 3) + (lane >> 3);
    int c = lane & 7;
    int4v v = *(const int4v*)(stg + r * 144 + ((c ^ (r & 7)) << 4));
    size_t m = (size_t)(m0 + wm + r);
    *(int4v*)(hout + (m << 8) + n0 + wn + c * 8) = v;
  }
}

// ---------------- head: out[b][o][h][w] = h2 @ W3 + b3 ----------------
__global__ __launch_bounds__(256) void k_head(const __hip_bfloat16* __restrict__ h2,
                                              const float* __restrict__ W3,
                                              const float* __restrict__ b3,
                                              float* __restrict__ out) {
  __shared__ __align__(16) __hip_bfloat16 hl[64 * 256];
  __shared__ float w3l[768];
  int tid = threadIdx.x;
  int m0 = blockIdx.x << 6;
#pragma unroll
  for (int i = 0; i < 8; ++i) {
    int idx = i * 256 + tid;
    *(int4v*)((char*)hl + idx * 16) = *(const int4v*)(h2 + ((size_t)m0 << 8) + idx * 8);
  }
  for (int i = tid; i < 768; i += 256) w3l[i] = W3[i];
  __syncthreads();
  int pix = tid >> 2, o = tid & 3;
  if (o < 3) {
    float acc = b3[o];
    for (int c0 = 0; c0 < 32; ++c0) {
      int c = (c0 + pix) & 31;
      bf16x8 v = *(const bf16x8*)((char*)hl + pix * 512 + c * 16);
#pragma unroll
      for (int j = 0; j < 8; ++j) {
        unsigned short u = (unsigned short)v[j];
        float hv = __uint_as_float((unsigned)u << 16);
        acc += hv * w3l[(c * 8 + j) * 3 + o];
      }
    }
    int m = m0 + pix;
    int b = m >> 14, hw = m & 16383;
    out[((b * 3 + o) << 14) + hw] = acc;
  }
}

extern "C" void kernel_launch(void* const* d_in, const int* in_sizes, int n_in,
                              void* d_out, int out_size, void* d_ws, size_t ws_size,
                              hipStream_t stream) {
  const float* xi = (const float*)d_in[0];
  const float* W0 = (const float*)d_in[1];
  const float* b0 = (const float*)d_in[2];
  const float* W1 = (const float*)d_in[3];
  const float* b1 = (const float*)d_in[4];
  const float* W2 = (const float*)d_in[5];
  const float* b2 = (const float*)d_in[6];
  const float* W3 = (const float*)d_in[7];
  const float* b3 = (const float*)d_in[8];
  float* out = (float*)d_out;
  char* ws = (char*)d_ws;

  __hip_bfloat16* xt  = (__hip_bfloat16*)(ws + 0);          //  8,388,608 B
  __hip_bfloat16* wt2 = (__hip_bfloat16*)(ws + 8388608);    //  1,638,400 B
  __hip_bfloat16* w1t = (__hip_bfloat16*)(ws + 10027008);   //    131,072 B
  __hip_bfloat16* w2t = (__hip_bfloat16*)(ws + 10158080);   //    131,072 B
  __hip_bfloat16* h0  = (__hip_bfloat16*)(ws + 10289152);   // 16,777,216 B (reused as h2)
  __hip_bfloat16* h1  = (__hip_bfloat16*)(ws + 27066368);   // 16,777,216 B

  k_transpose<<<dim3(512, 4, 2), 256, 0, stream>>>(xi, xt);
  k_prepw0<<<dim3(25, 8), 256, 0, stream>>>(W0, wt2);
  k_prepw12<<<dim3(8, 8, 2), 256, 0, stream>>>(W1, W2, w1t, w2t);
  k_conv<<<dim3(128, 4), 256, 0, stream>>>(xt, wt2, W0, b0, h0);
  k_layer<<<dim3(256, 2), 256, 0, stream>>>(h0, w1t, b1, h1);
  k_layer<<<dim3(256, 2), 256, 0, stream>>>(h1, w2t, b2, h0);
  k_head<<<512, 256, 0, stream>>>(h0, W3, b3, out);
}

// Round 7
// 285.167 us; speedup vs baseline: 2.7265x; 1.0225x over previous
//
#include <hip/hip_runtime.h>
#include <hip/hip_bf16.h>

typedef short bf16x8 __attribute__((ext_vector_type(8)));
typedef float f32x4 __attribute__((ext_vector_type(4)));
typedef int int4v __attribute__((ext_vector_type(4)));

#define OMEGA 30.0f

// ---------------- prep: transpose xi [B,C,H,W] f32 -> xt [B,HW,C] bf16 ----------------
__global__ __launch_bounds__(256) void k_transpose(const float* __restrict__ xi,
                                                   __hip_bfloat16* __restrict__ xt) {
  __shared__ float tile[32][33];
  int hw0 = blockIdx.x * 32, c0 = blockIdx.y * 32, b = blockIdx.z;
  int t = threadIdx.x;
  int r = t >> 5, cc = t & 31;
  const float* src = xi + (((size_t)b * 128 + c0) << 14) + hw0;
#pragma unroll
  for (int i = 0; i < 4; ++i)
    tile[r + i * 8][cc] = src[(size_t)(r + i * 8) * 16384 + cc];
  __syncthreads();
  __hip_bfloat16* dst = xt + (((size_t)b * 16384 + hw0) << 7) + c0;
#pragma unroll
  for (int i = 0; i < 4; ++i)
    dst[(size_t)(r + i * 8) * 128 + cc] = __float2bfloat16(tile[cc][r + i * 8]);
}

// ---------------- prep: W0 rows 0..3199 -> wt2[f][n][c] = W0[c*25+f][n] ----------------
__global__ __launch_bounds__(256) void k_prepw0(const float* __restrict__ W0,
                                                __hip_bfloat16* __restrict__ wt2) {
  __shared__ float tile[128][33];
  int f = blockIdx.x, nb = blockIdx.y;
  int t = threadIdx.x;
  int nn = t & 31, cr = t >> 5;  // cr 0..7
#pragma unroll
  for (int i = 0; i < 16; ++i) {
    int c = cr * 16 + i;
    tile[c][nn] = W0[(size_t)(c * 25 + f) * 256 + nb * 32 + nn];
  }
  __syncthreads();
#pragma unroll
  for (int i = 0; i < 16; ++i) {
    int idx = i * 256 + t;
    int n = idx >> 7, c = idx & 127;
    wt2[(size_t)f * 32768 + (size_t)(nb * 32 + n) * 128 + c] = __float2bfloat16(tile[c][n]);
  }
}

// ---------------- prep: w1t[n][k] = W1[k][n], w2t likewise; grid (8,8,2) ----------------
__global__ __launch_bounds__(256) void k_prepw12(const float* __restrict__ W1,
                                                 const float* __restrict__ W2,
                                                 __hip_bfloat16* __restrict__ w1t,
                                                 __hip_bfloat16* __restrict__ w2t) {
  __shared__ float tile[32][33];
  const float* src = blockIdx.z ? W2 : W1;
  __hip_bfloat16* dst = blockIdx.z ? w2t : w1t;
  int k0 = blockIdx.x * 32, n0 = blockIdx.y * 32;
  int t = threadIdx.x;
  int r = t >> 5, cc = t & 31;
#pragma unroll
  for (int i = 0; i < 4; ++i)
    tile[r + i * 8][cc] = src[(size_t)(k0 + r + i * 8) * 256 + n0 + cc];
  __syncthreads();
#pragma unroll
  for (int i = 0; i < 4; ++i)
    dst[(size_t)(n0 + r + i * 8) * 256 + k0 + cc] = __float2bfloat16(tile[cc][r + i * 8]);
}

// ---------------- conv 5x5 (128->256) + coords + bias + sin ----------------
// grid (128, 4), block 256 (4 waves). Static LDS 47104 B -> 3 blocks/CU.
// UNCHANGED from round 5 (82 us, proven).
__global__ __launch_bounds__(256) void k_conv(const __hip_bfloat16* __restrict__ xt,
                                              const __hip_bfloat16* __restrict__ wt2,
                                              const float* __restrict__ W0,
                                              const float* __restrict__ b0,
                                              __hip_bfloat16* __restrict__ h0) {
  __shared__ __align__(16) char Al[240 * 128];   // [12 rows x 20 px][64ch], swz s^(pos&7)
  __shared__ __align__(16) char Bl[2][64 * 128]; // dbuf [n][64ch], swz s^(n&7)
  int tid = threadIdx.x;
  int bx = blockIdx.x;
  int b = bx >> 6, tr = (bx >> 3) & 7, tc = bx & 7;
  int n0 = blockIdx.y << 6;
  int lane = tid & 63, wave = tid >> 6;
  int lr = lane & 15, lg = lane >> 4;

  float wA[4], wB[4], bb[4];
#pragma unroll
  for (int ni = 0; ni < 4; ++ni) {
    int n = n0 + (ni << 4) + lr;
    wA[ni] = W0[3200 * 256 + n];
    wB[ni] = W0[3201 * 256 + n];
    bb[ni] = b0[n];
  }

  int4v breg[2];
  auto loadB = [&](int i) {
    int cb = (i / 25) & 1, f = i % 25;
#pragma unroll
    for (int j = 0; j < 2; ++j) {
      int idx = j * 256 + tid;
      int n = idx >> 3, s = idx & 7;
      breg[j] = *(const int4v*)(wt2 + (size_t)(f * 256 + n0 + n) * 128 + cb * 64 + s * 8);
    }
  };
  auto writeB = [&](int i) {
    char* dst = Bl[i & 1];
#pragma unroll
    for (int j = 0; j < 2; ++j) {
      int idx = j * 256 + tid;
      int n = idx >> 3, s = idx & 7;
      *(int4v*)(dst + n * 128 + ((s ^ (n & 7)) << 4)) = breg[j];
    }
  };

  loadB(0);
  writeB(0);
  loadB(1);

  f32x4 acc[2][4] = {};

  for (int rh = 0; rh < 2; ++rh) {
    for (int half = 0; half < 2; ++half) {
      __syncthreads();  // prior readers of Al (incl. epilogue bounce) done
#pragma unroll
      for (int ii = 0; ii < 8; ++ii) {
        int idx = ii * 256 + tid;
        if (idx < 1920) {
          int pos = idx >> 3, s = idx & 7;
          int py = pos / 20, px_ = pos - py * 20;
          int gh = (tr << 4) + (rh << 3) + py - 2, gw = (tc << 4) + px_ - 2;
          int4v v = {0, 0, 0, 0};
          if ((unsigned)gh < 128u && (unsigned)gw < 128u)
            v = *(const int4v*)(xt + (((size_t)((b << 14) + (gh << 7) + gw)) << 7) + half * 64 + s * 8);
          *(int4v*)(Al + pos * 128 + ((s ^ (pos & 7)) << 4)) = v;
        }
      }
      __syncthreads();

      for (int f = 0; f < 25; ++f) {
        int i = rh * 50 + half * 25 + f;
        if (i < 99) writeB(i + 1);
        if (i < 98) loadB(i + 2);
        int fy = f / 5, fx = f - fy * 5;
        int px = lr + fx;
        char* Bbuf = Bl[i & 1];
#pragma unroll
        for (int ks = 0; ks < 2; ++ks) {
          int sk = (ks << 2) + lg;  // 0..7
          bf16x8 a[2], bw[4];
#pragma unroll
          for (int mi = 0; mi < 2; ++mi) {
            int fl = wave + (mi << 2);
            int pos = (fl + fy) * 20 + px;
            a[mi] = *(const bf16x8*)(Al + pos * 128 + ((sk ^ (pos & 7)) << 4));
          }
#pragma unroll
          for (int ni = 0; ni < 4; ++ni) {
            int nr = (ni << 4) + lr;
            bw[ni] = *(const bf16x8*)(Bbuf + nr * 128 + ((sk ^ (nr & 7)) << 4));
          }
#pragma unroll
          for (int mi = 0; mi < 2; ++mi)
#pragma unroll
            for (int ni = 0; ni < 4; ++ni)
              acc[mi][ni] = __builtin_amdgcn_mfma_f32_16x16x32_bf16(a[mi], bw[ni], acc[mi][ni], 0, 0, 0);
        }
        __syncthreads();
      }
    }

    char* stg = Al + wave * 4096;
#pragma unroll
    for (int mi = 0; mi < 2; ++mi) {
      int fl = wave + (mi << 2);
      int H = (tr << 4) + (rh << 3) + fl;
      float gy = -1.f + (2.f / 127.f) * (float)H;
#pragma unroll
      for (int j = 0; j < 4; ++j) {
        int cpx = (lg << 2) + j;
        int W = (tc << 4) + cpx;
        float gx = -1.f + (2.f / 127.f) * (float)W;
#pragma unroll
        for (int ni = 0; ni < 4; ++ni) {
          float v = acc[mi][ni][j] + bb[ni] + gx * wA[ni] + gy * wB[ni];
          unsigned short bits = __hip_bfloat16_raw(__float2bfloat16(sinf(OMEGA * v))).x;
          int n = (ni << 4) + lr;
          int c = n >> 3;
          *(unsigned short*)(stg + mi * 2048 + cpx * 128 + (((c ^ (cpx & 7)) << 4) | ((n & 7) << 1))) = bits;
        }
      }
    }
#pragma unroll
    for (int mi = 0; mi < 2; ++mi) {
      int fl = wave + (mi << 2);
      int H = (tr << 4) + (rh << 3) + fl;
#pragma unroll
      for (int i2 = 0; i2 < 2; ++i2) {
        int r = (i2 << 3) + (lane >> 3);
        int c = lane & 7;
        int4v v = *(const int4v*)(stg + mi * 2048 + r * 128 + ((c ^ (r & 7)) << 4));
        int m = (b << 14) + (H << 7) + (tc << 4) + r;
        *(int4v*)(h0 + (size_t)m * 256 + n0 + c * 8) = v;
      }
    }
    if (rh == 0) {
#pragma unroll
      for (int mi = 0; mi < 2; ++mi)
#pragma unroll
        for (int ni = 0; ni < 4; ++ni)
          acc[mi][ni] = f32x4{0.f, 0.f, 0.f, 0.f};
    }
  }
}

// ---------------- hidden layer: h_out = sin(30*(h_in @ W + b)) ----------------
// grid (256, 2), block 256 (4 waves 2x2). ZERO LDS, ZERO barriers.
// All fragments gathered directly from global (L2/L3-resident): each
// global_load_dwordx4 = 16 rows x 64B full lines. 8 base pointers, imm offsets.
__global__ __launch_bounds__(256) void k_layer(const __hip_bfloat16* __restrict__ hin,
                                               const __hip_bfloat16* __restrict__ wt,
                                               const float* __restrict__ bias,
                                               __hip_bfloat16* __restrict__ hout) {
  int tid = threadIdx.x;
  int m0 = blockIdx.x << 7, n0 = blockIdx.y << 7;
  int lane = tid & 63, wave = tid >> 6;
  int lr = lane & 15, lg = lane >> 4;
  int wm = (wave >> 1) << 6, wn = (wave & 1) << 6;

  const char* pA[4];
  const char* pB[4];
#pragma unroll
  for (int mi = 0; mi < 4; ++mi)
    pA[mi] = (const char*)(hin + ((size_t)(m0 + wm + (mi << 4) + lr) << 8)) + (lg << 4);
#pragma unroll
  for (int ni = 0; ni < 4; ++ni)
    pB[ni] = (const char*)(wt + ((size_t)(n0 + wn + (ni << 4) + lr) << 8)) + (lg << 4);

  f32x4 acc[4][4] = {};
#pragma unroll
  for (int ks = 0; ks < 8; ++ks) {
    bf16x8 a[4], bw[4];
#pragma unroll
    for (int mi = 0; mi < 4; ++mi) a[mi] = *(const bf16x8*)(pA[mi] + ks * 64);
#pragma unroll
    for (int ni = 0; ni < 4; ++ni) bw[ni] = *(const bf16x8*)(pB[ni] + ks * 64);
#pragma unroll
    for (int mi = 0; mi < 4; ++mi)
#pragma unroll
      for (int ni = 0; ni < 4; ++ni)
        acc[mi][ni] = __builtin_amdgcn_mfma_f32_16x16x32_bf16(a[mi], bw[ni], acc[mi][ni], 0, 0, 0);
  }

  float bb[4];
#pragma unroll
  for (int ni = 0; ni < 4; ++ni) bb[ni] = bias[n0 + wn + (ni << 4) + lr];
#pragma unroll
  for (int mi = 0; mi < 4; ++mi)
#pragma unroll
    for (int j = 0; j < 4; ++j) {
      size_t m = (size_t)(m0 + wm + (mi << 4) + (lg << 2) + j);
#pragma unroll
      for (int ni = 0; ni < 4; ++ni) {
        int n = n0 + wn + (ni << 4) + lr;
        hout[(m << 8) + n] = __float2bfloat16(sinf(OMEGA * (acc[mi][ni][j] + bb[ni])));
      }
    }
}

// ---------------- head: out[b][o][h][w] = h2 @ W3 + b3 ----------------
__global__ __launch_bounds__(256) void k_head(const __hip_bfloat16* __restrict__ h2,
                                              const float* __restrict__ W3,
                                              const float* __restrict__ b3,
                                              float* __restrict__ out) {
  __shared__ __align__(16) __hip_bfloat16 hl[64 * 256];
  __shared__ float w3l[768];
  int tid = threadIdx.x;
  int m0 = blockIdx.x << 6;
#pragma unroll
  for (int i = 0; i < 8; ++i) {
    int idx = i * 256 + tid;
    *(int4v*)((char*)hl + idx * 16) = *(const int4v*)(h2 + ((size_t)m0 << 8) + idx * 8);
  }
  for (int i = tid; i < 768; i += 256) w3l[i] = W3[i];
  __syncthreads();
  int pix = tid >> 2, o = tid & 3;
  if (o < 3) {
    float acc = b3[o];
    for (int c0 = 0; c0 < 32; ++c0) {
      int c = (c0 + pix) & 31;
      bf16x8 v = *(const bf16x8*)((char*)hl + pix * 512 + c * 16);
#pragma unroll
      for (int j = 0; j < 8; ++j) {
        unsigned short u = (unsigned short)v[j];
        float hv = __uint_as_float((unsigned)u << 16);
        acc += hv * w3l[(c * 8 + j) * 3 + o];
      }
    }
    int m = m0 + pix;
    int b = m >> 14, hw = m & 16383;
    out[((b * 3 + o) << 14) + hw] = acc;
  }
}

extern "C" void kernel_launch(void* const* d_in, const int* in_sizes, int n_in,
                              void* d_out, int out_size, void* d_ws, size_t ws_size,
                              hipStream_t stream) {
  const float* xi = (const float*)d_in[0];
  const float* W0 = (const float*)d_in[1];
  const float* b0 = (const float*)d_in[2];
  const float* W1 = (const float*)d_in[3];
  const float* b1 = (const float*)d_in[4];
  const float* W2 = (const float*)d_in[5];
  const float* b2 = (const float*)d_in[6];
  const float* W3 = (const float*)d_in[7];
  const float* b3 = (const float*)d_in[8];
  float* out = (float*)d_out;
  char* ws = (char*)d_ws;

  __hip_bfloat16* xt  = (__hip_bfloat16*)(ws + 0);          //  8,388,608 B
  __hip_bfloat16* wt2 = (__hip_bfloat16*)(ws + 8388608);    //  1,638,400 B
  __hip_bfloat16* w1t = (__hip_bfloat16*)(ws + 10027008);   //    131,072 B
  __hip_bfloat16* w2t = (__hip_bfloat16*)(ws + 10158080);   //    131,072 B
  __hip_bfloat16* h0  = (__hip_bfloat16*)(ws + 10289152);   // 16,777,216 B (reused as h2)
  __hip_bfloat16* h1  = (__hip_bfloat16*)(ws + 27066368);   // 16,777,216 B

  k_transpose<<<dim3(512, 4, 2), 256, 0, stream>>>(xi, xt);
  k_prepw0<<<dim3(25, 8), 256, 0, stream>>>(W0, wt2);
  k_prepw12<<<dim3(8, 8, 2), 256, 0, stream>>>(W1, W2, w1t, w2t);
  k_conv<<<dim3(128, 4), 256, 0, stream>>>(xt, wt2, W0, b0, h0);
  k_layer<<<dim3(256, 2), 256, 0, stream>>>(h0, w1t, b1, h1);
  k_layer<<<dim3(256, 2), 256, 0, stream>>>(h1, w2t, b2, h0);
  k_head<<<512, 256, 0, stream>>>(h0, W3, b3, out);
}

// Round 8
// 219.055 us; speedup vs baseline: 3.5494x; 1.3018x over previous
//
#include <hip/hip_runtime.h>
#include <hip/hip_bf16.h>

typedef short bf16x8 __attribute__((ext_vector_type(8)));
typedef float f32x4 __attribute__((ext_vector_type(4)));
typedef int int4v __attribute__((ext_vector_type(4)));

#define OMEGA 30.0f

// ---------------- unified prep: transpose xi, repack W0, transpose W1/W2 ----------------
// grid 4424: [0,4096) transpose, [4096,4296) prepw0, [4296,4424) prepw12
__global__ __launch_bounds__(256) void k_prep(const float* __restrict__ xi,
                                              const float* __restrict__ W0,
                                              const float* __restrict__ W1,
                                              const float* __restrict__ W2,
                                              __hip_bfloat16* __restrict__ xt,
                                              __hip_bfloat16* __restrict__ wt2,
                                              __hip_bfloat16* __restrict__ w1t,
                                              __hip_bfloat16* __restrict__ w2t) {
  __shared__ float tile[128][33];
  int bx = blockIdx.x, t = threadIdx.x;
  if (bx < 4096) {
    // xi [B,C,H,W] f32 -> xt [B,HW,C] bf16
    int b = bx >> 11, c0 = ((bx >> 9) & 3) << 5, hw0 = (bx & 511) << 5;
    int r = t >> 5, cc = t & 31;
    const float* src = xi + (((size_t)b * 128 + c0) << 14) + hw0;
#pragma unroll
    for (int i = 0; i < 4; ++i)
      tile[r + i * 8][cc] = src[(size_t)(r + i * 8) * 16384 + cc];
    __syncthreads();
    __hip_bfloat16* dst = xt + (((size_t)b * 16384 + hw0) << 7) + c0;
#pragma unroll
    for (int i = 0; i < 4; ++i)
      dst[(size_t)(r + i * 8) * 128 + cc] = __float2bfloat16(tile[cc][r + i * 8]);
  } else if (bx < 4296) {
    // W0 rows 0..3199 -> wt2[f][n][c] = W0[c*25+f][n]
    int q = bx - 4096, f = q >> 3, nb = q & 7;
    int nn = t & 31, cr = t >> 5;
#pragma unroll
    for (int i = 0; i < 16; ++i) {
      int c = cr * 16 + i;
      tile[c][nn] = W0[(size_t)(c * 25 + f) * 256 + nb * 32 + nn];
    }
    __syncthreads();
#pragma unroll
    for (int i = 0; i < 16; ++i) {
      int idx = i * 256 + t;
      int n = idx >> 7, c = idx & 127;
      wt2[(size_t)f * 32768 + (size_t)(nb * 32 + n) * 128 + c] = __float2bfloat16(tile[c][n]);
    }
  } else {
    // w1t[n][k] = W1[k][n]; w2t likewise
    int rI = bx - 4296;
    const float* src = (rI >> 6) ? W2 : W1;
    __hip_bfloat16* dst = (rI >> 6) ? w2t : w1t;
    int k0 = ((rI >> 3) & 7) << 5, n0 = (rI & 7) << 5;
    int r = t >> 5, cc = t & 31;
#pragma unroll
    for (int i = 0; i < 4; ++i)
      tile[r + i * 8][cc] = src[(size_t)(k0 + r + i * 8) * 256 + n0 + cc];
    __syncthreads();
#pragma unroll
    for (int i = 0; i < 4; ++i)
      dst[(size_t)(n0 + r + i * 8) * 256 + k0 + cc] = __float2bfloat16(tile[cc][r + i * 8]);
  }
}

// ---------------- conv 5x5 (128->256) + coords + bias + sin ----------------
// grid (128, 4), block 256 (4 waves). Static LDS 47104 B. UNCHANGED (81 us, proven).
__global__ __launch_bounds__(256) void k_conv(const __hip_bfloat16* __restrict__ xt,
                                              const __hip_bfloat16* __restrict__ wt2,
                                              const float* __restrict__ W0,
                                              const float* __restrict__ b0,
                                              __hip_bfloat16* __restrict__ h0) {
  __shared__ __align__(16) char Al[240 * 128];   // [12 rows x 20 px][64ch], swz s^(pos&7)
  __shared__ __align__(16) char Bl[2][64 * 128]; // dbuf [n][64ch], swz s^(n&7)
  int tid = threadIdx.x;
  int bx = blockIdx.x;
  int b = bx >> 6, tr = (bx >> 3) & 7, tc = bx & 7;
  int n0 = blockIdx.y << 6;
  int lane = tid & 63, wave = tid >> 6;
  int lr = lane & 15, lg = lane >> 4;

  float wA[4], wB[4], bb[4];
#pragma unroll
  for (int ni = 0; ni < 4; ++ni) {
    int n = n0 + (ni << 4) + lr;
    wA[ni] = W0[3200 * 256 + n];
    wB[ni] = W0[3201 * 256 + n];
    bb[ni] = b0[n];
  }

  int4v breg[2];
  auto loadB = [&](int i) {
    int cb = (i / 25) & 1, f = i % 25;
#pragma unroll
    for (int j = 0; j < 2; ++j) {
      int idx = j * 256 + tid;
      int n = idx >> 3, s = idx & 7;
      breg[j] = *(const int4v*)(wt2 + (size_t)(f * 256 + n0 + n) * 128 + cb * 64 + s * 8);
    }
  };
  auto writeB = [&](int i) {
    char* dst = Bl[i & 1];
#pragma unroll
    for (int j = 0; j < 2; ++j) {
      int idx = j * 256 + tid;
      int n = idx >> 3, s = idx & 7;
      *(int4v*)(dst + n * 128 + ((s ^ (n & 7)) << 4)) = breg[j];
    }
  };

  loadB(0);
  writeB(0);
  loadB(1);

  f32x4 acc[2][4] = {};

  for (int rh = 0; rh < 2; ++rh) {
    for (int half = 0; half < 2; ++half) {
      __syncthreads();
#pragma unroll
      for (int ii = 0; ii < 8; ++ii) {
        int idx = ii * 256 + tid;
        if (idx < 1920) {
          int pos = idx >> 3, s = idx & 7;
          int py = pos / 20, px_ = pos - py * 20;
          int gh = (tr << 4) + (rh << 3) + py - 2, gw = (tc << 4) + px_ - 2;
          int4v v = {0, 0, 0, 0};
          if ((unsigned)gh < 128u && (unsigned)gw < 128u)
            v = *(const int4v*)(xt + (((size_t)((b << 14) + (gh << 7) + gw)) << 7) + half * 64 + s * 8);
          *(int4v*)(Al + pos * 128 + ((s ^ (pos & 7)) << 4)) = v;
        }
      }
      __syncthreads();

      for (int f = 0; f < 25; ++f) {
        int i = rh * 50 + half * 25 + f;
        if (i < 99) writeB(i + 1);
        if (i < 98) loadB(i + 2);
        int fy = f / 5, fx = f - fy * 5;
        int px = lr + fx;
        char* Bbuf = Bl[i & 1];
#pragma unroll
        for (int ks = 0; ks < 2; ++ks) {
          int sk = (ks << 2) + lg;
          bf16x8 a[2], bw[4];
#pragma unroll
          for (int mi = 0; mi < 2; ++mi) {
            int fl = wave + (mi << 2);
            int pos = (fl + fy) * 20 + px;
            a[mi] = *(const bf16x8*)(Al + pos * 128 + ((sk ^ (pos & 7)) << 4));
          }
#pragma unroll
          for (int ni = 0; ni < 4; ++ni) {
            int nr = (ni << 4) + lr;
            bw[ni] = *(const bf16x8*)(Bbuf + nr * 128 + ((sk ^ (nr & 7)) << 4));
          }
#pragma unroll
          for (int mi = 0; mi < 2; ++mi)
#pragma unroll
            for (int ni = 0; ni < 4; ++ni)
              acc[mi][ni] = __builtin_amdgcn_mfma_f32_16x16x32_bf16(a[mi], bw[ni], acc[mi][ni], 0, 0, 0);
        }
        __syncthreads();
      }
    }

    char* stg = Al + wave * 4096;
#pragma unroll
    for (int mi = 0; mi < 2; ++mi) {
      int fl = wave + (mi << 2);
      int H = (tr << 4) + (rh << 3) + fl;
      float gy = -1.f + (2.f / 127.f) * (float)H;
#pragma unroll
      for (int j = 0; j < 4; ++j) {
        int cpx = (lg << 2) + j;
        int W = (tc << 4) + cpx;
        float gx = -1.f + (2.f / 127.f) * (float)W;
#pragma unroll
        for (int ni = 0; ni < 4; ++ni) {
          float v = acc[mi][ni][j] + bb[ni] + gx * wA[ni] + gy * wB[ni];
          unsigned short bits = __hip_bfloat16_raw(__float2bfloat16(sinf(OMEGA * v))).x;
          int n = (ni << 4) + lr;
          int c = n >> 3;
          *(unsigned short*)(stg + mi * 2048 + cpx * 128 + (((c ^ (cpx & 7)) << 4) | ((n & 7) << 1))) = bits;
        }
      }
    }
#pragma unroll
    for (int mi = 0; mi < 2; ++mi) {
      int fl = wave + (mi << 2);
      int H = (tr << 4) + (rh << 3) + fl;
#pragma unroll
      for (int i2 = 0; i2 < 2; ++i2) {
        int r = (i2 << 3) + (lane >> 3);
        int c = lane & 7;
        int4v v = *(const int4v*)(stg + mi * 2048 + r * 128 + ((c ^ (r & 7)) << 4));
        int m = (b << 14) + (H << 7) + (tc << 4) + r;
        *(int4v*)(h0 + (size_t)m * 256 + n0 + c * 8) = v;
      }
    }
    if (rh == 0) {
#pragma unroll
      for (int mi = 0; mi < 2; ++mi)
#pragma unroll
        for (int ni = 0; ni < 4; ++ni)
          acc[mi][ni] = f32x4{0.f, 0.f, 0.f, 0.f};
    }
  }
}

// ---------------- fused MLP: h0 -> L1 -> L2 -> head, per 32-pixel block ----------------
// grid 1024, block 256 (4 waves: mg=wave>>1 picks 16 rows, nh=wave&1 picks 128 cols).
// LDS: one [32][256] bf16 tile (slot-swizzled), reused h1 then h2; + w3 stage.
__global__ __launch_bounds__(256, 4) void k_fused(const __hip_bfloat16* __restrict__ h0,
                                                  const __hip_bfloat16* __restrict__ w1t,
                                                  const float* __restrict__ b1,
                                                  const __hip_bfloat16* __restrict__ w2t,
                                                  const float* __restrict__ b2,
                                                  const float* __restrict__ W3,
                                                  const float* __restrict__ b3,
                                                  float* __restrict__ out) {
  __shared__ __align__(16) char Hl[32 * 512];  // [r][slot sl^(r&31)][8 bf16]
  __shared__ float w3l[768];
  int tid = threadIdx.x;
  int m0 = blockIdx.x << 5;
  int lane = tid & 63, wave = tid >> 6;
  int lr = lane & 15, lg = lane >> 4;
  int mg = wave >> 1, nh = wave & 1;

  for (int i = tid; i < 768; i += 256) w3l[i] = W3[i];

  int mrow = m0 + (mg << 4) + lr;
  const char* pA0 = (const char*)(h0 + ((size_t)mrow << 8)) + (lg << 4);
  const char* pB1[8];
  const char* pB2[8];
  float bb1[8], bb2[8];
#pragma unroll
  for (int ni = 0; ni < 8; ++ni) {
    int n = (nh << 7) + (ni << 4) + lr;
    pB1[ni] = (const char*)(w1t + ((size_t)n << 8)) + (lg << 4);
    pB2[ni] = (const char*)(w2t + ((size_t)n << 8)) + (lg << 4);
    bb1[ni] = b1[n];
    bb2[ni] = b2[n];
  }

  // ---- GEMM1: A gathered from h0 (global), B = w1t (global, L2-resident)
  f32x4 acc[8] = {};
#pragma unroll
  for (int ks = 0; ks < 8; ++ks) {
    bf16x8 a = *(const bf16x8*)(pA0 + ks * 64);
    bf16x8 bw[8];
#pragma unroll
    for (int ni = 0; ni < 8; ++ni) bw[ni] = *(const bf16x8*)(pB1[ni] + ks * 64);
#pragma unroll
    for (int ni = 0; ni < 8; ++ni)
      acc[ni] = __builtin_amdgcn_mfma_f32_16x16x32_bf16(a, bw[ni], acc[ni], 0, 0, 0);
  }
  // h1 = sin(30*(acc+b1)) -> LDS
#pragma unroll
  for (int j = 0; j < 4; ++j) {
    int r = (mg << 4) + (lg << 2) + j;
#pragma unroll
    for (int ni = 0; ni < 8; ++ni) {
      int c = (nh << 7) + (ni << 4) + lr;
      unsigned short bits =
          __hip_bfloat16_raw(__float2bfloat16(sinf(OMEGA * (acc[ni][j] + bb1[ni])))).x;
      int sl = (c >> 3) ^ (r & 31);
      *(unsigned short*)(Hl + r * 512 + (sl << 4) + ((c & 7) << 1)) = bits;
    }
  }
  __syncthreads();

  // ---- GEMM2: A from LDS h1, B = w2t (global)
  int rA = (mg << 4) + lr;
  f32x4 acc2[8] = {};
#pragma unroll
  for (int ks = 0; ks < 8; ++ks) {
    int sk = (ks << 2) + lg;
    bf16x8 a = *(const bf16x8*)(Hl + rA * 512 + ((sk ^ (rA & 31)) << 4));
    bf16x8 bw[8];
#pragma unroll
    for (int ni = 0; ni < 8; ++ni) bw[ni] = *(const bf16x8*)(pB2[ni] + ks * 64);
#pragma unroll
    for (int ni = 0; ni < 8; ++ni)
      acc2[ni] = __builtin_amdgcn_mfma_f32_16x16x32_bf16(a, bw[ni], acc2[ni], 0, 0, 0);
  }
  __syncthreads();  // everyone done reading h1
  // h2 -> LDS (same tile)
#pragma unroll
  for (int j = 0; j < 4; ++j) {
    int r = (mg << 4) + (lg << 2) + j;
#pragma unroll
    for (int ni = 0; ni < 8; ++ni) {
      int c = (nh << 7) + (ni << 4) + lr;
      unsigned short bits =
          __hip_bfloat16_raw(__float2bfloat16(sinf(OMEGA * (acc2[ni][j] + bb2[ni])))).x;
      int sl = (c >> 3) ^ (r & 31);
      *(unsigned short*)(Hl + r * 512 + (sl << 4) + ((c & 7) << 1)) = bits;
    }
  }
  __syncthreads();

  // ---- head: 8 threads per pixel, k-chunks of 32, shfl-xor reduce
  int pix = tid >> 3, s = tid & 7;
  float a0 = 0.f, a1 = 0.f, a2 = 0.f;
#pragma unroll
  for (int q = 0; q < 4; ++q) {
    int sl = ((s << 2) + q) ^ (pix & 31);
    bf16x8 hv = *(const bf16x8*)(Hl + pix * 512 + (sl << 4));
#pragma unroll
    for (int e = 0; e < 8; ++e) {
      int k = (s << 5) + (q << 3) + e;
      float h = __uint_as_float((unsigned)(unsigned short)hv[e] << 16);
      a0 += h * w3l[k * 3 + 0];
      a1 += h * w3l[k * 3 + 1];
      a2 += h * w3l[k * 3 + 2];
    }
  }
#pragma unroll
  for (int d = 1; d < 8; d <<= 1) {
    a0 += __shfl_xor(a0, d);
    a1 += __shfl_xor(a1, d);
    a2 += __shfl_xor(a2, d);
  }
  if (s < 3) {
    int m = m0 + pix;
    int b = m >> 14, hw = m & 16383;
    float v = (s == 0) ? (a0 + b3[0]) : (s == 1) ? (a1 + b3[1]) : (a2 + b3[2]);
    out[((b * 3 + s) << 14) + hw] = v;
  }
}

extern "C" void kernel_launch(void* const* d_in, const int* in_sizes, int n_in,
                              void* d_out, int out_size, void* d_ws, size_t ws_size,
                              hipStream_t stream) {
  const float* xi = (const float*)d_in[0];
  const float* W0 = (const float*)d_in[1];
  const float* b0 = (const float*)d_in[2];
  const float* W1 = (const float*)d_in[3];
  const float* b1 = (const float*)d_in[4];
  const float* W2 = (const float*)d_in[5];
  const float* b2 = (const float*)d_in[6];
  const float* W3 = (const float*)d_in[7];
  const float* b3 = (const float*)d_in[8];
  float* out = (float*)d_out;
  char* ws = (char*)d_ws;

  __hip_bfloat16* xt  = (__hip_bfloat16*)(ws + 0);          //  8,388,608 B
  __hip_bfloat16* wt2 = (__hip_bfloat16*)(ws + 8388608);    //  1,638,400 B
  __hip_bfloat16* w1t = (__hip_bfloat16*)(ws + 10027008);   //    131,072 B
  __hip_bfloat16* w2t = (__hip_bfloat16*)(ws + 10158080);   //    131,072 B
  __hip_bfloat16* h0  = (__hip_bfloat16*)(ws + 10289152);   // 16,777,216 B

  k_prep<<<4424, 256, 0, stream>>>(xi, W0, W1, W2, xt, wt2, w1t, w2t);
  k_conv<<<dim3(128, 4), 256, 0, stream>>>(xt, wt2, W0, b0, h0);
  k_fused<<<1024, 256, 0, stream>>>(h0, w1t, b1, w2t, b2, W3, b3, out);
}

// Round 10
// 209.260 us; speedup vs baseline: 3.7155x; 1.0468x over previous
//
#include <hip/hip_runtime.h>
#include <hip/hip_bf16.h>

typedef short bf16x8 __attribute__((ext_vector_type(8)));
typedef float f32x4 __attribute__((ext_vector_type(4)));
typedef int int4v __attribute__((ext_vector_type(4)));

#define OMEGA 30.0f

// sin(30*z) via HW v_sin (period 2pi*t, input in revolutions): 3 VALU ops vs ~100 for ocml sinf.
// |30z| <~ few rad (SIREN init), so fract reduction is lossless; v_sin err ~1e-6 << bf16 lsb.
__device__ __forceinline__ float fast_sin30(float z) {
  float t = z * 4.7746483f;  // 30/(2*pi)
  t = __builtin_amdgcn_fractf(t);
  return __builtin_amdgcn_sinf(t);
}

// ---------------- unified prep: transpose xi, repack W0, transpose W1/W2 ----------------
// grid 4424: [0,4096) transpose, [4096,4296) prepw0, [4296,4424) prepw12
__global__ __launch_bounds__(256) void k_prep(const float* __restrict__ xi,
                                              const float* __restrict__ W0,
                                              const float* __restrict__ W1,
                                              const float* __restrict__ W2,
                                              __hip_bfloat16* __restrict__ xt,
                                              __hip_bfloat16* __restrict__ wt2,
                                              __hip_bfloat16* __restrict__ w1t,
                                              __hip_bfloat16* __restrict__ w2t) {
  __shared__ float tile[128][33];
  int bx = blockIdx.x, t = threadIdx.x;
  if (bx < 4096) {
    int b = bx >> 11, c0 = ((bx >> 9) & 3) << 5, hw0 = (bx & 511) << 5;
    int r = t >> 5, cc = t & 31;
    const float* src = xi + (((size_t)b * 128 + c0) << 14) + hw0;
#pragma unroll
    for (int i = 0; i < 4; ++i)
      tile[r + i * 8][cc] = src[(size_t)(r + i * 8) * 16384 + cc];
    __syncthreads();
    __hip_bfloat16* dst = xt + (((size_t)b * 16384 + hw0) << 7) + c0;
#pragma unroll
    for (int i = 0; i < 4; ++i)
      dst[(size_t)(r + i * 8) * 128 + cc] = __float2bfloat16(tile[cc][r + i * 8]);
  } else if (bx < 4296) {
    int q = bx - 4096, f = q >> 3, nb = q & 7;
    int nn = t & 31, cr = t >> 5;
#pragma unroll
    for (int i = 0; i < 16; ++i) {
      int c = cr * 16 + i;
      tile[c][nn] = W0[(size_t)(c * 25 + f) * 256 + nb * 32 + nn];
    }
    __syncthreads();
#pragma unroll
    for (int i = 0; i < 16; ++i) {
      int idx = i * 256 + t;
      int n = idx >> 7, c = idx & 127;
      wt2[(size_t)f * 32768 + (size_t)(nb * 32 + n) * 128 + c] = __float2bfloat16(tile[c][n]);
    }
  } else {
    int rI = bx - 4296;
    const float* src = (rI >> 6) ? W2 : W1;
    __hip_bfloat16* dst = (rI >> 6) ? w2t : w1t;
    int k0 = ((rI >> 3) & 7) << 5, n0 = (rI & 7) << 5;
    int r = t >> 5, cc = t & 31;
#pragma unroll
    for (int i = 0; i < 4; ++i)
      tile[r + i * 8][cc] = src[(size_t)(k0 + r + i * 8) * 256 + n0 + cc];
    __syncthreads();
#pragma unroll
    for (int i = 0; i < 4; ++i)
      dst[(size_t)(n0 + r + i * 8) * 256 + k0 + cc] = __float2bfloat16(tile[cc][r + i * 8]);
  }
}

// ---------------- conv 5x5 (128->256) + coords + bias + sin ----------------
// grid (128, 4), block 256 (4 waves). Static LDS 47104 B. Structure unchanged
// from round 5 (proven); only sinf -> fast_sin30.
__global__ __launch_bounds__(256) void k_conv(const __hip_bfloat16* __restrict__ xt,
                                              const __hip_bfloat16* __restrict__ wt2,
                                              const float* __restrict__ W0,
                                              const float* __restrict__ b0,
                                              __hip_bfloat16* __restrict__ h0) {
  __shared__ __align__(16) char Al[240 * 128];   // [12 rows x 20 px][64ch], swz s^(pos&7)
  __shared__ __align__(16) char Bl[2][64 * 128]; // dbuf [n][64ch], swz s^(n&7)
  int tid = threadIdx.x;
  int bx = blockIdx.x;
  int b = bx >> 6, tr = (bx >> 3) & 7, tc = bx & 7;
  int n0 = blockIdx.y << 6;
  int lane = tid & 63, wave = tid >> 6;
  int lr = lane & 15, lg = lane >> 4;

  float wA[4], wB[4], bb[4];
#pragma unroll
  for (int ni = 0; ni < 4; ++ni) {
    int n = n0 + (ni << 4) + lr;
    wA[ni] = W0[3200 * 256 + n];
    wB[ni] = W0[3201 * 256 + n];
    bb[ni] = b0[n];
  }

  int4v breg[2];
  auto loadB = [&](int i) {
    int cb = (i / 25) & 1, f = i % 25;
#pragma unroll
    for (int j = 0; j < 2; ++j) {
      int idx = j * 256 + tid;
      int n = idx >> 3, s = idx & 7;
      breg[j] = *(const int4v*)(wt2 + (size_t)(f * 256 + n0 + n) * 128 + cb * 64 + s * 8);
    }
  };
  auto writeB = [&](int i) {
    char* dst = Bl[i & 1];
#pragma unroll
    for (int j = 0; j < 2; ++j) {
      int idx = j * 256 + tid;
      int n = idx >> 3, s = idx & 7;
      *(int4v*)(dst + n * 128 + ((s ^ (n & 7)) << 4)) = breg[j];
    }
  };

  loadB(0);
  writeB(0);
  loadB(1);

  f32x4 acc[2][4] = {};

  for (int rh = 0; rh < 2; ++rh) {
    for (int half = 0; half < 2; ++half) {
      __syncthreads();
#pragma unroll
      for (int ii = 0; ii < 8; ++ii) {
        int idx = ii * 256 + tid;
        if (idx < 1920) {
          int pos = idx >> 3, s = idx & 7;
          int py = pos / 20, px_ = pos - py * 20;
          int gh = (tr << 4) + (rh << 3) + py - 2, gw = (tc << 4) + px_ - 2;
          int4v v = {0, 0, 0, 0};
          if ((unsigned)gh < 128u && (unsigned)gw < 128u)
            v = *(const int4v*)(xt + (((size_t)((b << 14) + (gh << 7) + gw)) << 7) + half * 64 + s * 8);
          *(int4v*)(Al + pos * 128 + ((s ^ (pos & 7)) << 4)) = v;
        }
      }
      __syncthreads();

      for (int f = 0; f < 25; ++f) {
        int i = rh * 50 + half * 25 + f;
        if (i < 99) writeB(i + 1);
        if (i < 98) loadB(i + 2);
        int fy = f / 5, fx = f - fy * 5;
        int px = lr + fx;
        char* Bbuf = Bl[i & 1];
#pragma unroll
        for (int ks = 0; ks < 2; ++ks) {
          int sk = (ks << 2) + lg;
          bf16x8 a[2], bw[4];
#pragma unroll
          for (int mi = 0; mi < 2; ++mi) {
            int fl = wave + (mi << 2);
            int pos = (fl + fy) * 20 + px;
            a[mi] = *(const bf16x8*)(Al + pos * 128 + ((sk ^ (pos & 7)) << 4));
          }
#pragma unroll
          for (int ni = 0; ni < 4; ++ni) {
            int nr = (ni << 4) + lr;
            bw[ni] = *(const bf16x8*)(Bbuf + nr * 128 + ((sk ^ (nr & 7)) << 4));
          }
#pragma unroll
          for (int mi = 0; mi < 2; ++mi)
#pragma unroll
            for (int ni = 0; ni < 4; ++ni)
              acc[mi][ni] = __builtin_amdgcn_mfma_f32_16x16x32_bf16(a[mi], bw[ni], acc[mi][ni], 0, 0, 0);
        }
        __syncthreads();
      }
    }

    char* stg = Al + wave * 4096;
#pragma unroll
    for (int mi = 0; mi < 2; ++mi) {
      int fl = wave + (mi << 2);
      int H = (tr << 4) + (rh << 3) + fl;
      float gy = -1.f + (2.f / 127.f) * (float)H;
#pragma unroll
      for (int j = 0; j < 4; ++j) {
        int cpx = (lg << 2) + j;
        int W = (tc << 4) + cpx;
        float gx = -1.f + (2.f / 127.f) * (float)W;
#pragma unroll
        for (int ni = 0; ni < 4; ++ni) {
          float v = acc[mi][ni][j] + bb[ni] + gx * wA[ni] + gy * wB[ni];
          unsigned short bits = __hip_bfloat16_raw(__float2bfloat16(fast_sin30(v))).x;
          int n = (ni << 4) + lr;
          int c = n >> 3;
          *(unsigned short*)(stg + mi * 2048 + cpx * 128 + (((c ^ (cpx & 7)) << 4) | ((n & 7) << 1))) = bits;
        }
      }
    }
#pragma unroll
    for (int mi = 0; mi < 2; ++mi) {
      int fl = wave + (mi << 2);
      int H = (tr << 4) + (rh << 3) + fl;
#pragma unroll
      for (int i2 = 0; i2 < 2; ++i2) {
        int r = (i2 << 3) + (lane >> 3);
        int c = lane & 7;
        int4v v = *(const int4v*)(stg + mi * 2048 + r * 128 + ((c ^ (r & 7)) << 4));
        int m = (b << 14) + (H << 7) + (tc << 4) + r;
        *(int4v*)(h0 + (size_t)m * 256 + n0 + c * 8) = v;
      }
    }
    if (rh == 0) {
#pragma unroll
      for (int mi = 0; mi < 2; ++mi)
#pragma unroll
        for (int ni = 0; ni < 4; ++ni)
          acc[mi][ni] = f32x4{0.f, 0.f, 0.f, 0.f};
    }
  }
}

// ---------------- fused MLP: h0 -> L1 -> L2 -> head, per 32-pixel block ----------------
// grid 1024, block 256 (4 waves). Structure unchanged from round 8; sinf -> fast_sin30.
__global__ __launch_bounds__(256, 4) void k_fused(const __hip_bfloat16* __restrict__ h0,
                                                  const __hip_bfloat16* __restrict__ w1t,
                                                  const float* __restrict__ b1,
                                                  const __hip_bfloat16* __restrict__ w2t,
                                                  const float* __restrict__ b2,
                                                  const float* __restrict__ W3,
                                                  const float* __restrict__ b3,
                                                  float* __restrict__ out) {
  __shared__ __align__(16) char Hl[32 * 512];  // [r][slot sl^(r&31)][8 bf16]
  __shared__ float w3l[768];
  int tid = threadIdx.x;
  int m0 = blockIdx.x << 5;
  int lane = tid & 63, wave = tid >> 6;
  int lr = lane & 15, lg = lane >> 4;
  int mg = wave >> 1, nh = wave & 1;

  for (int i = tid; i < 768; i += 256) w3l[i] = W3[i];

  int mrow = m0 + (mg << 4) + lr;
  const char* pA0 = (const char*)(h0 + ((size_t)mrow << 8)) + (lg << 4);
  const char* pB1[8];
  const char* pB2[8];
  float bb1[8], bb2[8];
#pragma unroll
  for (int ni = 0; ni < 8; ++ni) {
    int n = (nh << 7) + (ni << 4) + lr;
    pB1[ni] = (const char*)(w1t + ((size_t)n << 8)) + (lg << 4);
    pB2[ni] = (const char*)(w2t + ((size_t)n << 8)) + (lg << 4);
    bb1[ni] = b1[n];
    bb2[ni] = b2[n];
  }

  // ---- GEMM1: A gathered from h0 (global), B = w1t (global, L2-resident)
  f32x4 acc[8] = {};
#pragma unroll
  for (int ks = 0; ks < 8; ++ks) {
    bf16x8 a = *(const bf16x8*)(pA0 + ks * 64);
    bf16x8 bw[8];
#pragma unroll
    for (int ni = 0; ni < 8; ++ni) bw[ni] = *(const bf16x8*)(pB1[ni] + ks * 64);
#pragma unroll
    for (int ni = 0; ni < 8; ++ni)
      acc[ni] = __builtin_amdgcn_mfma_f32_16x16x32_bf16(a, bw[ni], acc[ni], 0, 0, 0);
  }
#pragma unroll
  for (int j = 0; j < 4; ++j) {
    int r = (mg << 4) + (lg << 2) + j;
#pragma unroll
    for (int ni = 0; ni < 8; ++ni) {
      int c = (nh << 7) + (ni << 4) + lr;
      unsigned short bits =
          __hip_bfloat16_raw(__float2bfloat16(fast_sin30(acc[ni][j] + bb1[ni]))).x;
      int sl = (c >> 3) ^ (r & 31);
      *(unsigned short*)(Hl + r * 512 + (sl << 4) + ((c & 7) << 1)) = bits;
    }
  }
  __syncthreads();

  // ---- GEMM2: A from LDS h1, B = w2t (global)
  int rA = (mg << 4) + lr;
  f32x4 acc2[8] = {};
#pragma unroll
  for (int ks = 0; ks < 8; ++ks) {
    int sk = (ks << 2) + lg;
    bf16x8 a = *(const bf16x8*)(Hl + rA * 512 + ((sk ^ (rA & 31)) << 4));
    bf16x8 bw[8];
#pragma unroll
    for (int ni = 0; ni < 8; ++ni) bw[ni] = *(const bf16x8*)(pB2[ni] + ks * 64);
#pragma unroll
    for (int ni = 0; ni < 8; ++ni)
      acc2[ni] = __builtin_amdgcn_mfma_f32_16x16x32_bf16(a, bw[ni], acc2[ni], 0, 0, 0);
  }
  __syncthreads();  // everyone done reading h1
#pragma unroll
  for (int j = 0; j < 4; ++j) {
    int r = (mg << 4) + (lg << 2) + j;
#pragma unroll
    for (int ni = 0; ni < 8; ++ni) {
      int c = (nh << 7) + (ni << 4) + lr;
      unsigned short bits =
          __hip_bfloat16_raw(__float2bfloat16(fast_sin30(acc2[ni][j] + bb2[ni]))).x;
      int sl = (c >> 3) ^ (r & 31);
      *(unsigned short*)(Hl + r * 512 + (sl << 4) + ((c & 7) << 1)) = bits;
    }
  }
  __syncthreads();

  // ---- head: 8 threads per pixel, k-chunks of 32, shfl-xor reduce
  int pix = tid >> 3, s = tid & 7;
  float a0 = 0.f, a1 = 0.f, a2 = 0.f;
#pragma unroll
  for (int q = 0; q < 4; ++q) {
    int sl = ((s << 2) + q) ^ (pix & 31);
    bf16x8 hv = *(const bf16x8*)(Hl + pix * 512 + (sl << 4));
#pragma unroll
    for (int e = 0; e < 8; ++e) {
      int k = (s << 5) + (q << 3) + e;
      float h = __uint_as_float((unsigned)(unsigned short)hv[e] << 16);
      a0 += h * w3l[k * 3 + 0];
      a1 += h * w3l[k * 3 + 1];
      a2 += h * w3l[k * 3 + 2];
    }
  }
#pragma unroll
  for (int d = 1; d < 8; d <<= 1) {
    a0 += __shfl_xor(a0, d);
    a1 += __shfl_xor(a1, d);
    a2 += __shfl_xor(a2, d);
  }
  if (s < 3) {
    int m = m0 + pix;
    int b = m >> 14, hw = m & 16383;
    float v = (s == 0) ? (a0 + b3[0]) : (s == 1) ? (a1 + b3[1]) : (a2 + b3[2]);
    out[((b * 3 + s) << 14) + hw] = v;
  }
}

extern "C" void kernel_launch(void* const* d_in, const int* in_sizes, int n_in,
                              void* d_out, int out_size, void* d_ws, size_t ws_size,
                              hipStream_t stream) {
  const float* xi = (const float*)d_in[0];
  const float* W0 = (const float*)d_in[1];
  const float* b0 = (const float*)d_in[2];
  const float* W1 = (const float*)d_in[3];
  const float* b1 = (const float*)d_in[4];
  const float* W2 = (const float*)d_in[5];
  const float* b2 = (const float*)d_in[6];
  const float* W3 = (const float*)d_in[7];
  const float* b3 = (const float*)d_in[8];
  float* out = (float*)d_out;
  char* ws = (char*)d_ws;

  __hip_bfloat16* xt  = (__hip_bfloat16*)(ws + 0);          //  8,388,608 B
  __hip_bfloat16* wt2 = (__hip_bfloat16*)(ws + 8388608);    //  1,638,400 B
  __hip_bfloat16* w1t = (__hip_bfloat16*)(ws + 10027008);   //    131,072 B
  __hip_bfloat16* w2t = (__hip_bfloat16*)(ws + 10158080);   //    131,072 B
  __hip_bfloat16* h0  = (__hip_bfloat16*)(ws + 10289152);   // 16,777,216 B

  k_prep<<<4424, 256, 0, stream>>>(xi, W0, W1, W2, xt, wt2, w1t, w2t);
  k_conv<<<dim3(128, 4), 256, 0, stream>>>(xt, wt2, W0, b0, h0);
  k_fused<<<1024, 256, 0, stream>>>(h0, w1t, b1, w2t, b2, W3, b3, out);
}